// Round 2
// baseline (245.253 us; speedup 1.0000x reference)
//
#include <hip/hip_runtime.h>

// Problem constants
#define LDIM 16384
#define KDIM 288
#define ODIM 64
#define BDIM 8

#define MT 128          // l-rows per block
#define LPAD 132        // LDS row stride in floats (16B-aligned: 132*4=528)

typedef float f32x4 __attribute__((ext_vector_type(4)));
typedef short bf16x8 __attribute__((ext_vector_type(8)));  // 8 bf16 in 4 VGPRs

// fp32 -> bf16 round-to-nearest-even
__device__ __forceinline__ short f2bf(float f) {
  unsigned u = __builtin_bit_cast(unsigned, f);
  unsigned r = u + 0x7FFFu + ((u >> 16) & 1u);
  return (short)(r >> 16);
}

// ---------------------------------------------------------------------------
// Pre-kernel, grid=10: blocks 0..8 swizzle W k-chunk kc=blockIdx into MFMA
// B-fragment order (bf16); block 9 computes cw[o] = -gamma * sum_k w[k][o]^2.
// wv[k][o] = w_flat[k*64 + o]  (memory reinterpretation per reference)
// ---------------------------------------------------------------------------
__global__ __launch_bounds__(256) void gauss_pre(const float* __restrict__ w,
                                                 const float* __restrict__ gammap,
                                                 short* __restrict__ wfrag,
                                                 float* __restrict__ cw) {
  int tid = threadIdx.x;
  int blk = blockIdx.x;

  if (blk < 9) {
    // 256 fragments for this kc (4 nt * 64 lanes)
    int kc = blk;
    int ln = tid & 63;
    int nt = tid >> 6;
    int k0 = kc * 32 + (ln >> 4) * 8;
    int n = nt * 16 + (ln & 15);
    bf16x8 v;
#pragma unroll
    for (int j = 0; j < 8; ++j) v[j] = f2bf(w[(k0 + j) * 64 + n]);
    *(bf16x8*)(wfrag + ((kc * 4 + nt) * 64 + ln) * 8) = v;
  } else {
    // w2 reduction: 4 segments of 72 k's per output col
    __shared__ float red[256];
    int o = tid & 63;
    int seg = tid >> 6;
    float s = 0.f;
#pragma unroll 8
    for (int k = seg * 72; k < seg * 72 + 72; ++k) {
      float v = w[k * 64 + o];
      s += v * v;
    }
    red[tid] = s;
    __syncthreads();
    if (tid < 64) {
      float t = red[tid] + red[tid + 64] + red[tid + 128] + red[tid + 192];
      cw[tid] = -gammap[0] * t;
    }
  }
}

// ---------------------------------------------------------------------------
// Main kernel: block=256 (4 waves), M-tile=128 l-rows, N=64, K=288 in 9x32.
// Coalesced global->reg->LDS staging (double-buffered, software-pipelined),
// ds_read A-fragments + fp32->bf16 convert (|x|^2 for free), 8 MFMA/kc/wave.
// Grid = B*L/128 = 1024 blocks -> 4 blocks/CU.
// ---------------------------------------------------------------------------
__global__ __launch_bounds__(256, 4) void gauss_main(
    const float* __restrict__ x, const short* __restrict__ wfrag,
    const float* __restrict__ cw, const float* __restrict__ bias,
    const float* __restrict__ gammap, float* __restrict__ out) {
  __shared__ float abuf[2][32 * LPAD];

  const int tid = threadIdx.x;
  const int lane = tid & 63;
  const int wvid = tid >> 6;
  const int m = lane & 15;
  const int quad = lane >> 4;

  const long g0 = (long)blockIdx.x * MT;  // global row (b*L + l)
  const int bidx = (int)(g0 >> 14);       // L = 16384
  const int l0 = (int)(g0 & (LDIM - 1));

  const float* xb = x + (long)bidx * ((long)KDIM * LDIM) + l0;

  // Staging assignment: thread covers 4 float4's; f = tid + i*256,
  // row = f>>5 (k within chunk), col4 = f&31 (float4 along l).
  const int srow0 = tid >> 5;       // rows srow0 + i*8
  const int scol = (tid & 31) * 4;  // float offset within row

  const f32x4 zero = {0.f, 0.f, 0.f, 0.f};
  f32x4 acc[2][4];
#pragma unroll
  for (int t = 0; t < 2; ++t)
#pragma unroll
    for (int nt = 0; nt < 4; ++nt) acc[t][nt] = zero;
  float s2[2] = {0.f, 0.f};

  // ---- prologue: stage kc=0 into buf 0
  float4 rs[4];
#pragma unroll
  for (int i = 0; i < 4; ++i) {
    int row = srow0 + i * 8;
    rs[i] = *(const float4*)(xb + (long)row * LDIM + scol);
  }
#pragma unroll
  for (int i = 0; i < 4; ++i) {
    int row = srow0 + i * 8;
    *(float4*)&abuf[0][row * LPAD + scol] = rs[i];
  }
  __syncthreads();

#pragma unroll 1
  for (int kc = 0; kc < 9; ++kc) {
    const int pb = kc & 1;

    // ---- issue global loads for kc+1 (fill latency with compute below)
    if (kc < 8) {
      const float* xn = xb + (long)((kc + 1) * 32) * LDIM;
#pragma unroll
      for (int i = 0; i < 4; ++i) {
        int row = srow0 + i * 8;
        rs[i] = *(const float4*)(xn + (long)row * LDIM + scol);
      }
    }

    // ---- B fragments for this kc (L2-hot, 4 x b128 per lane)
    bf16x8 bfr[4];
    const short* wp = wfrag + ((kc * 4) * 64 + lane) * 8;
#pragma unroll
    for (int nt = 0; nt < 4; ++nt) bfr[nt] = *(const bf16x8*)(wp + nt * 512);

    // ---- compute from buf pb
#pragma unroll
    for (int t = 0; t < 2; ++t) {
      const float* ap = &abuf[pb][(quad * 8) * LPAD + wvid * 32 + t * 16 + m];
      float a[8];
#pragma unroll
      for (int j = 0; j < 8; ++j) a[j] = ap[j * LPAD];
      bf16x8 afr;
#pragma unroll
      for (int j = 0; j < 8; ++j) {
        s2[t] += a[j] * a[j];
        afr[j] = f2bf(a[j]);
      }
#pragma unroll
      for (int nt = 0; nt < 4; ++nt)
        acc[t][nt] =
            __builtin_amdgcn_mfma_f32_16x16x32_bf16(afr, bfr[nt], acc[t][nt], 0, 0, 0);
    }

    // ---- write staged kc+1 regs to the other buffer
    if (kc < 8) {
#pragma unroll
      for (int i = 0; i < 4; ++i) {
        int row = srow0 + i * 8;
        *(float4*)&abuf[pb ^ 1][row * LPAD + scol] = rs[i];
      }
    }
    __syncthreads();
  }

  // ---- finish |x|^2 across quads
#pragma unroll
  for (int t = 0; t < 2; ++t) {
    s2[t] += __shfl_xor(s2[t], 16, 64);
    s2[t] += __shfl_xor(s2[t], 32, 64);
  }

  const float gamma = gammap[0];
  float cwv[4], bv[4];
#pragma unroll
  for (int nt = 0; nt < 4; ++nt) {
    int col = nt * 16 + m;
    cwv[nt] = cw[col];
    bv[nt] = bias[col];
  }

  const float coef = 2.f * gamma;
  // Epilogue: C/D layout col = lane&15, row = quad*4 + r
#pragma unroll
  for (int t = 0; t < 2; ++t) {
#pragma unroll
    for (int r = 0; r < 4; ++r) {
      int row = quad * 4 + r;
      float x2v = __shfl(s2[t], (lane & 48) | row, 64);
      float cx = -gamma * x2v;
      long grow = g0 + wvid * 32 + t * 16 + row;
      float* po = out + grow * 64 + m;
#pragma unroll
      for (int nt = 0; nt < 4; ++nt) {
        float e = coef * acc[t][nt][r] + (cx + cwv[nt]);  // -gamma*d2
        po[nt * 16] = __expf(e) + bv[nt];
      }
    }
  }
}

extern "C" void kernel_launch(void* const* d_in, const int* in_sizes, int n_in,
                              void* d_out, int out_size, void* d_ws, size_t ws_size,
                              hipStream_t stream) {
  const float* x = (const float*)d_in[0];      // [8, 288, 16384]
  const float* w = (const float*)d_in[1];      // [64, 32, 3, 3] -> flat 18432
  const float* b = (const float*)d_in[2];      // [64]
  const float* gamma = (const float*)d_in[3];  // scalar
  float* out = (float*)d_out;                  // [8, 16384, 64]

  short* wfrag = (short*)d_ws;                // 18432 bf16 = 36864 B
  float* cw = (float*)((char*)d_ws + 36864);  // 64 floats

  gauss_pre<<<10, 256, 0, stream>>>(w, gamma, wfrag, cw);
  gauss_main<<<1024, 256, 0, stream>>>(x, wfrag, cw, b, gamma, out);
}

// Round 3
// 230.045 us; speedup vs baseline: 1.0661x; 1.0661x over previous
//
#include <hip/hip_runtime.h>

// Problem constants
#define LDIM 16384
#define KDIM 288
#define ODIM 64
#define BDIM 8

typedef float f32x4 __attribute__((ext_vector_type(4)));
typedef short bf16x8 __attribute__((ext_vector_type(8)));  // 8 bf16 in 4 VGPRs

// fp32 -> bf16 round-to-nearest-even
__device__ __forceinline__ short f2bf(float f) {
  unsigned u = __builtin_bit_cast(unsigned, f);
  unsigned r = u + 0x7FFFu + ((u >> 16) & 1u);
  return (short)(r >> 16);
}

// ---------------------------------------------------------------------------
// Pre-kernel, grid=10: blocks 0..8 swizzle W k-chunk kc=blockIdx into MFMA
// B-fragment order (bf16); block 9 computes cw[o] = -gamma * sum_k w[k][o]^2.
// wv[k][o] = w_flat[k*64 + o]  (memory reinterpretation per reference)
// ---------------------------------------------------------------------------
__global__ __launch_bounds__(256) void gauss_pre(const float* __restrict__ w,
                                                 const float* __restrict__ gammap,
                                                 short* __restrict__ wfrag,
                                                 float* __restrict__ cw) {
  int tid = threadIdx.x;
  int blk = blockIdx.x;

  if (blk < 9) {
    int kc = blk;
    int ln = tid & 63;
    int nt = tid >> 6;
    int k0 = kc * 32 + (ln >> 4) * 8;
    int n = nt * 16 + (ln & 15);
    bf16x8 v;
#pragma unroll
    for (int j = 0; j < 8; ++j) v[j] = f2bf(w[(k0 + j) * 64 + n]);
    *(bf16x8*)(wfrag + ((kc * 4 + nt) * 64 + ln) * 8) = v;
  } else {
    __shared__ float red[256];
    int o = tid & 63;
    int seg = tid >> 6;
    float s = 0.f;
#pragma unroll 8
    for (int k = seg * 72; k < seg * 72 + 72; ++k) {
      float v = w[k * 64 + o];
      s += v * v;
    }
    red[tid] = s;
    __syncthreads();
    if (tid < 64) {
      float t = red[tid] + red[tid + 64] + red[tid + 128] + red[tid + 192];
      cw[tid] = -gammap[0] * t;
    }
  }
}

// ---------------------------------------------------------------------------
// Main kernel v3 (m97-style): async global->LDS staging (width=16, no VGPR
// round trip, no ds_writes), double-buffered, prefetch distance 2.
// LDS layout is UNPADDED 32x128 (global_load_lds forces wave-linear order).
// Epilogue transposes C-fragments through the freed LDS so every store
// instruction writes 1 KB contiguous. Block=256 (4 waves), M-tile=128,
// grid=1024 -> 4 blocks/CU (LDS 32 KB).
// ---------------------------------------------------------------------------
__global__ __launch_bounds__(256, 4) void gauss_main(
    const float* __restrict__ x, const short* __restrict__ wfrag,
    const float* __restrict__ cw, const float* __restrict__ bias,
    const float* __restrict__ gammap, float* __restrict__ out) {
  __shared__ float abuf[2][32 * 128];  // 2 x 16 KB, no pad

  const int tid = threadIdx.x;
  const int lane = tid & 63;
  const int wvid = tid >> 6;
  const int m = lane & 15;
  const int quad = lane >> 4;

  const long g0 = (long)blockIdx.x * 128;  // global row (b*L + l)
  const int bidx = (int)(g0 >> 14);        // L = 16384
  const int l0 = (int)(g0 & (LDIM - 1));

  const float* xb = x + (long)bidx * ((long)KDIM * LDIM) + l0;

  // Staging: instruction s = wvid*4+i covers kc-local rows {2s, 2s+1};
  // lane's 16 B: global row 2s+(lane>>5), col (lane&31)*4; LDS = base+lane*16.
  const int srow = (lane >> 5);        // 0/1 within the 2-row chunk
  const int scolf = (lane & 31) * 4;   // float col

#define STAGE(KC, BUF)                                                         \
  {                                                                            \
    const float* xsrc = xb + (long)((KC) * 32) * LDIM;                         \
    _Pragma("unroll") for (int i = 0; i < 4; ++i) {                            \
      int s = wvid * 4 + i;                                                    \
      const float* gp = xsrc + (long)(2 * s + srow) * LDIM + scolf;            \
      __builtin_amdgcn_global_load_lds(                                        \
          (const __attribute__((address_space(1))) unsigned int*)(void*)gp,    \
          (__attribute__((address_space(3))) unsigned int*)&abuf[BUF][s * 256],\
          16, 0, 0);                                                           \
    }                                                                          \
  }

  const f32x4 zero = {0.f, 0.f, 0.f, 0.f};
  f32x4 acc[2][4];
#pragma unroll
  for (int t = 0; t < 2; ++t)
#pragma unroll
    for (int nt = 0; nt < 4; ++nt) acc[t][nt] = zero;
  float s2[2] = {0.f, 0.f};

  // ---- prologue: stage kc=0 and kc=1
  STAGE(0, 0)
  STAGE(1, 1)
  __syncthreads();

#pragma unroll 1
  for (int kc = 0; kc < 9; ++kc) {
    const int pb = kc & 1;

    // B fragments for this kc (L2-hot, 4 x b128 per lane)
    bf16x8 bfr[4];
    const short* wp = wfrag + ((kc * 4) * 64 + lane) * 8;
#pragma unroll
    for (int nt = 0; nt < 4; ++nt) bfr[nt] = *(const bf16x8*)(wp + nt * 512);

    // compute from buf pb
#pragma unroll
    for (int t = 0; t < 2; ++t) {
      const float* ap = &abuf[pb][(quad * 8) * 128 + wvid * 32 + t * 16 + m];
      float a[8];
#pragma unroll
      for (int j = 0; j < 8; ++j) a[j] = ap[j * 128];
      bf16x8 afr;
#pragma unroll
      for (int j = 0; j < 8; ++j) {
        s2[t] += a[j] * a[j];
        afr[j] = f2bf(a[j]);
      }
#pragma unroll
      for (int nt = 0; nt < 4; ++nt)
        acc[t][nt] =
            __builtin_amdgcn_mfma_f32_16x16x32_bf16(afr, bfr[nt], acc[t][nt], 0, 0, 0);
    }

    __syncthreads();          // frees buf pb; drains in-flight kc+1 loads
    if (kc < 7) STAGE(kc + 2, pb)
  }

  // ---- finish |x|^2 across quads
#pragma unroll
  for (int t = 0; t < 2; ++t) {
    s2[t] += __shfl_xor(s2[t], 16, 64);
    s2[t] += __shfl_xor(s2[t], 32, 64);
  }

  const float gamma = gammap[0];
  float cwv[4], bv[4];
#pragma unroll
  for (int nt = 0; nt < 4; ++nt) {
    int col = nt * 16 + m;
    cwv[nt] = cw[col];
    bv[nt] = bias[col];
  }

  // ---- epilogue: compute t(out) in C-layout, transpose via LDS, store 1 KB/instr
  // Wave's private 2048-float region of the (now free) abuf.
  float* ob = &abuf[0][0] + wvid * 2048;
  const float coef = 2.f * gamma;
#pragma unroll
  for (int t = 0; t < 2; ++t) {
#pragma unroll
    for (int r = 0; r < 4; ++r) {
      int row = quad * 4 + r;
      float x2v = __shfl(s2[t], (lane & 48) | row, 64);
      float cx = -gamma * x2v;
      int lr = t * 16 + row;  // 0..31 within wave tile
#pragma unroll
      for (int nt = 0; nt < 4; ++nt) {
        float e = coef * acc[t][nt][r] + (cx + cwv[nt]);  // -gamma*d2
        ob[lr * 64 + nt * 16 + m] = __expf(e) + bv[nt];
      }
    }
  }
  __syncthreads();  // order LDS writes before cross-lane reads (also lgkm drain)

  // flat f = j*256 + lane*4 -> lr = j*4 + (lane>>4), col = (lane&15)*4
  float* outw = out + (g0 + wvid * 32) * 64;
#pragma unroll
  for (int j = 0; j < 8; ++j) {
    f32x4 v = *(f32x4*)&ob[j * 256 + lane * 4];
    *(f32x4*)(outw + (j * 4 + (lane >> 4)) * 64 + (lane & 15) * 4) = v;
  }
}

extern "C" void kernel_launch(void* const* d_in, const int* in_sizes, int n_in,
                              void* d_out, int out_size, void* d_ws, size_t ws_size,
                              hipStream_t stream) {
  const float* x = (const float*)d_in[0];      // [8, 288, 16384]
  const float* w = (const float*)d_in[1];      // [64, 32, 3, 3] -> flat 18432
  const float* b = (const float*)d_in[2];      // [64]
  const float* gamma = (const float*)d_in[3];  // scalar
  float* out = (float*)d_out;                  // [8, 16384, 64]

  short* wfrag = (short*)d_ws;                // 18432 bf16 = 36864 B
  float* cw = (float*)((char*)d_ws + 36864);  // 64 floats

  gauss_pre<<<10, 256, 0, stream>>>(w, gamma, wfrag, cw);
  gauss_main<<<1024, 256, 0, stream>>>(x, wfrag, cw, b, gamma, out);
}